// Round 13
// baseline (102.068 us; speedup 1.0000x reference)
//
#include <hip/hip_runtime.h>
#include <cmath>

#define HH 256
#define WW 256
#define RAD 12
#define KLEN 25
#define NMAPS 512
#define ESTRIP 32
#define NSTRIP (HH / ESTRIP)   // 8 strips per map
#define RING 29                // 24 carried + 5 fresh slots per macro-iter

typedef float v2f __attribute__((ext_vector_type(2)));

// ---------------------------------------------------------------------------
// Kernel A: 256-thread blocks = 4 INDEPENDENT strip-waves; 64 lanes x 4 cols.
// Software-pipelined row schedule (1-row skew, fully static), R12 structure.
// R13: horizontal conv packed as v_pk_fma_f32 pairs:
//   accA={acc0,acc1} += kf[d]*{w[d],w[d+1]};  accB={acc2,acc3} += kf[d]*{w[d+2],w[d+3]}
// even pairs free from ds_read_b128 quads; 13 odd pairs formed in-register.
// Scalar summation order identical to R12 (ascending d) -> bitwise-same output.
// No min-waves launch-bounds arg (R9/R10: it caps VGPR and forces spill).
// ---------------------------------------------------------------------------
__global__ __launch_bounds__(256) void blur_peak_strip(
    const float* __restrict__ in,
    float* __restrict__ sval,
    int* __restrict__ sidx,
    int* __restrict__ scnt)
{
    __shared__ __align__(16) float vrow[4][2][WW + 2 * RAD];  // per-wave dbuf

    const int tid  = threadIdx.x;
    const int l    = tid & 63;           // lane, owns cols 4l..4l+3
    const int wv   = tid >> 6;
    const int sid  = blockIdx.x * 4 + wv;    // strip id 0..4095
    const int m     = sid >> 3;              // map
    const int strip = sid & 7;               // strip within map
    const float4* map4 = reinterpret_cast<const float4*>(in) + (size_t)m * (HH * WW / 4);

    const int e0 = strip * ESTRIP;
    const int o0 = e0 - 1;

    // Gaussian taps (identical float32 math to R2-R12; folds at compile time).
    float kf[KLEN];
    {
        float s = 0.f; float h[RAD + 1];
#pragma unroll
        for (int i = 0; i <= RAD; ++i) {
            float tt = (float)(i - RAD);
            h[i] = expf(-(tt * tt) / 18.0f);
            s += (i < RAD) ? 2.f * h[i] : h[i];
        }
#pragma unroll
        for (int i = 0; i <= RAD; ++i) h[i] /= s;
#pragma unroll
        for (int i = 0; i < KLEN; ++i) kf[i] = h[(i <= RAD) ? i : (2 * RAD - i)];
    }

    // Ring: slot i holds padded[oT + i], oT = o0 + 5*T; padded[q] = raw[mirr(q-12)]
    v2f rxy[RING], rzw[RING];
#pragma unroll
    for (int i = 0; i < RING; ++i) {
        int q = o0 + i - RAD;
        int r = (q < 0) ? (-q - 1) : q;    // top mirror only
        float4 t4 = map4[(size_t)r * (WW / 4) + l];
        rxy[i] = (v2f){t4.x, t4.y};
        rzw[i] = (v2f){t4.z, t4.w};
    }

    float4 g0v  = make_float4(0.f, 0.f, 0.f, 0.f);
    float4 gm1v = g0v, gm2v = g0v;
    float bval = -1.f;
    int   bidx = 0x7FFFFFFF;
    int   cnt  = 0;
    float4 pf0, pf1, pf2, pf3, pf4;

#define PREFETCH(TT)                                                          \
    {                                                                         \
        int rb = o0 + 5 * (TT) + 17;                                          \
        int r0 = rb, r1 = rb + 1, r2 = rb + 2, r3 = rb + 3, r4 = rb + 4;      \
        if (r0 > HH - 1) r0 = 2 * HH - 1 - r0;                                \
        if (r1 > HH - 1) r1 = 2 * HH - 1 - r1;                                \
        if (r2 > HH - 1) r2 = 2 * HH - 1 - r2;                                \
        if (r3 > HH - 1) r3 = 2 * HH - 1 - r3;                                \
        if (r4 > HH - 1) r4 = 2 * HH - 1 - r4;                                \
        pf0 = map4[(size_t)r0 * (WW / 4) + l];                                \
        pf1 = map4[(size_t)r1 * (WW / 4) + l];                                \
        pf2 = map4[(size_t)r2 * (WW / 4) + l];                                \
        pf3 = map4[(size_t)r3 * (WW / 4) + l];                                \
        pf4 = map4[(size_t)r4 * (WW / 4) + l];                                \
    }

#define ROTATE()                                                              \
    {                                                                         \
        _Pragma("unroll")                                                     \
        for (int i = 0; i < RING - 5; ++i) {                                  \
            rxy[i] = rxy[i + 5]; rzw[i] = rzw[i + 5];                         \
        }                                                                     \
        rxy[24] = (v2f){pf0.x, pf0.y}; rzw[24] = (v2f){pf0.z, pf0.w};         \
        rxy[25] = (v2f){pf1.x, pf1.y}; rzw[25] = (v2f){pf1.z, pf1.w};         \
        rxy[26] = (v2f){pf2.x, pf2.y}; rzw[26] = (v2f){pf2.z, pf2.w};         \
        rxy[27] = (v2f){pf3.x, pf3.y}; rzw[27] = (v2f){pf3.z, pf3.w};         \
        rxy[28] = (v2f){pf4.x, pf4.y}; rzw[28] = (v2f){pf4.z, pf4.w};         \
    }

// VC(t) from ring slots PP..PP+24 and write v(t) into buf[(TP)&1]
#define VCW(PP, TP)                                                           \
    {                                                                         \
        v2f vxy = (v2f){0.f, 0.f};                                            \
        v2f vzw = (v2f){0.f, 0.f};                                            \
        _Pragma("unroll")                                                     \
        for (int d = 0; d < KLEN; ++d) {                                      \
            vxy += kf[d] * rxy[(PP) + d];                                     \
            vzw += kf[d] * rzw[(PP) + d];                                     \
        }                                                                     \
        float* wb = vrow[wv][(TP) & 1];                                       \
        reinterpret_cast<float4*>(wb + RAD)[l] =                              \
            make_float4(vxy.x, vxy.y, vzw.x, vzw.y);                          \
        if (l < 3)   reinterpret_cast<float4*>(wb)[2 - l]   =                 \
            make_float4(vzw.y, vzw.x, vxy.y, vxy.x);                          \
        if (l >= 61) reinterpret_cast<float4*>(wb)[130 - l] =                 \
            make_float4(vzw.y, vzw.x, vxy.y, vxy.x);                          \
    }

// HC of row held in rd0..rd6 -> shift g history.  Packed pk-FMA version:
// accA = {acc0,acc1}, accB = {acc2,acc3}; per tap d (ascending, same order
// as R12's scalar chains): accA += kf[d]*{w[d],w[d+1]},
//                          accB += kf[d]*{w[d+2],w[d+3]}.
#define HC()                                                                  \
    {                                                                         \
        const float4 rda[7] = {rd0, rd1, rd2, rd3, rd4, rd5, rd6};            \
        v2f we[14];                                                           \
        _Pragma("unroll")                                                     \
        for (int k = 0; k < 7; ++k) {                                         \
            we[2 * k]     = (v2f){rda[k].x, rda[k].y};                        \
            we[2 * k + 1] = (v2f){rda[k].z, rda[k].w};                        \
        }                                                                     \
        v2f wo[13];                                                           \
        _Pragma("unroll")                                                     \
        for (int j = 0; j < 13; ++j) wo[j] = (v2f){we[j].y, we[j + 1].x};     \
        v2f accA = (v2f){0.f, 0.f};                                           \
        v2f accB = (v2f){0.f, 0.f};                                           \
        _Pragma("unroll")                                                     \
        for (int d = 0; d < KLEN; ++d) {                                      \
            if (d & 1) {                                                      \
                accA += kf[d] * wo[(d - 1) / 2];                              \
                accB += kf[d] * wo[(d + 1) / 2];                              \
            } else {                                                          \
                accA += kf[d] * we[d / 2];                                    \
                accB += kf[d] * we[d / 2 + 1];                                \
            }                                                                 \
        }                                                                     \
        gm2v = gm1v; gm1v = g0v;                                              \
        g0v = make_float4(accA.x, accA.y, accB.x, accB.y);                    \
    }

// eval row EROW (center gm1v), raw values from ring slot SLOT
#define EV(SLOT, EROW)                                                        \
    {                                                                         \
        const int erow = (EROW);                                              \
        float lf0 = __shfl_up(gm1v.w, 1);   if (l == 0)  lf0 = 0.f;           \
        float rt3 = __shfl_down(gm1v.x, 1); if (l == 63) rt3 = 0.f;           \
        const bool etop = (erow == 0), ebot = (erow == HH - 1);               \
        const float gm1a[4] = {gm1v.x, gm1v.y, gm1v.z, gm1v.w};               \
        const float gm2a[4] = {gm2v.x, gm2v.y, gm2v.z, gm2v.w};               \
        const float g0a[4]  = {g0v.x,  g0v.y,  g0v.z,  g0v.w};                \
        const float mva[4]  = {rxy[SLOT].x, rxy[SLOT].y,                      \
                               rzw[SLOT].x, rzw[SLOT].y};                     \
        _Pragma("unroll")                                                     \
        for (int q = 0; q < 4; ++q) {                                         \
            float gE = gm1a[q];                                               \
            float up = etop ? 0.f : gm2a[q];                                  \
            float dn = ebot ? 0.f : g0a[q];                                   \
            float lf = (q == 0) ? lf0 : gm1a[q - 1];                          \
            float rt = (q == 3) ? rt3 : gm1a[q + 1];                          \
            float mx = fmaxf(fmaxf(up, dn), fmaxf(lf, rt));                   \
            bool pk = (gE >= mx) && (gE > 0.01f);                             \
            cnt += pk ? 1 : 0;                                                \
            float mv = mva[q];                                                \
            int fi = erow * WW + 4 * l + q;                                   \
            bool upd = pk && (mv > bval);                                     \
            bval = upd ? mv : bval;                                           \
            bidx = upd ? fi : bidx;                                           \
        }                                                                     \
    }

// full pipelined row: t = 5*TB+PP. RD(t-1) -> VC(t)+write -> HC(t-1) -> EV(t-2)
#define ROW_FULL(TB, PP)                                                      \
    {                                                                         \
        const int tpar = ((TB) + (PP)) & 1;   /* parity of t since 5T+PP */   \
        const float4* rb4 =                                                   \
            reinterpret_cast<const float4*>(vrow[wv][tpar ^ 1]);              \
        float4 rd0 = rb4[l + 0], rd1 = rb4[l + 1], rd2 = rb4[l + 2],          \
               rd3 = rb4[l + 3], rd4 = rb4[l + 4], rd5 = rb4[l + 5],          \
               rd6 = rb4[l + 6];                                              \
        VCW(PP, tpar);                                                        \
        __builtin_amdgcn_wave_barrier();                                      \
        HC();                                                                 \
        EV((PP) + 10, o0 + 5 * (TB) + (PP) - 2);                              \
    }

// warmup row without eval (t = PP, TB=0)
#define ROW_NOEV(PP)                                                          \
    {                                                                         \
        const int tpar = (PP) & 1;                                            \
        const float4* rb4 =                                                   \
            reinterpret_cast<const float4*>(vrow[wv][tpar ^ 1]);              \
        float4 rd0 = rb4[l + 0], rd1 = rb4[l + 1], rd2 = rb4[l + 2],          \
               rd3 = rb4[l + 3], rd4 = rb4[l + 4], rd5 = rb4[l + 5],          \
               rd6 = rb4[l + 6];                                              \
        VCW(PP, PP);                                                          \
        __builtin_amdgcn_wave_barrier();                                      \
        HC();                                                                 \
    }

    // ---- T = 0: t=0 (VC only), t=1,2 (no eval), t=3,4 (full) ----
    PREFETCH(0);
    VCW(0, 0);
    __builtin_amdgcn_wave_barrier();
    ROW_NOEV(1);
    ROW_NOEV(2);
    ROW_FULL(0, 3);
    ROW_FULL(0, 4);
    ROTATE();

    // ---- main: T = 1..5, rows t = 5T..5T+4, all full ----
#pragma unroll 1
    for (int T = 1; T < 6; ++T) {
        PREFETCH(T);
        ROW_FULL(T, 0);
        ROW_FULL(T, 1);
        ROW_FULL(T, 2);
        ROW_FULL(T, 3);
        ROW_FULL(T, 4);
        ROTATE();
    }

    // ---- T = 6: t=30..33 full; t=34 tail (RD+HC+EV only) ----
    ROW_FULL(6, 0);
    ROW_FULL(6, 1);
    ROW_FULL(6, 2);
    ROW_FULL(6, 3);
    {
        // t = 34: read v(33) from buf[33&1]=buf[1], HC(33), EV(32)
        const float4* rb4 = reinterpret_cast<const float4*>(vrow[wv][1]);
        float4 rd0 = rb4[l + 0], rd1 = rb4[l + 1], rd2 = rb4[l + 2],
               rd3 = rb4[l + 3], rd4 = rb4[l + 4], rd5 = rb4[l + 5],
               rd6 = rb4[l + 6];
        HC();
        EV(14, o0 + 32);
    }

#undef ROW_NOEV
#undef ROW_FULL
#undef EV
#undef HC
#undef VCW
#undef ROTATE
#undef PREFETCH

    // ---- 64-lane butterfly: (max val, min idx on tie), sum count ----
#pragma unroll
    for (int off = 32; off > 0; off >>= 1) {
        float v2 = __shfl_xor(bval, off);
        int   i2 = __shfl_xor(bidx, off);
        int   c2 = __shfl_xor(cnt,  off);
        if (v2 > bval || (v2 == bval && i2 < bidx)) { bval = v2; bidx = i2; }
        cnt += c2;
    }
    if (l == 0) { sval[sid] = bval; sidx[sid] = bidx; scnt[sid] = cnt; }
}

// ---------------------------------------------------------------------------
// Kernel B: per-map combine strips + 5x5 window sums at winner + output logic
// ---------------------------------------------------------------------------
__global__ __launch_bounds__(256) void finalize_kernel(
    const float* __restrict__ in,
    const float* __restrict__ sval,
    const int* __restrict__ sidx,
    const int* __restrict__ scnt,
    float* __restrict__ out)
{
    int t = blockIdx.x * blockDim.x + threadIdx.x;
    if (t >= NMAPS) return;

    float BV = -1.f; int BI = 0x7FFFFFFF; int C = 0;
#pragma unroll
    for (int s2 = 0; s2 < NSTRIP; ++s2) {
        int k = t * NSTRIP + s2;
        float v = sval[k]; int i = sidx[k];
        if (v > BV || (v == BV && i < BI)) { BV = v; BI = i; }
        C += scnt[k];
    }

    bool valid = (C == 1) || ((C > 1) && (BV >= 0.8f));

    float kx = -999.999f, ky = -999.999f, conf = 0.f;
    if (valid) {
        int pr = BI / WW, pc = BI % WW;
        const float* map = in + (size_t)t * HH * WW;
        float S = 0.f, SX = 0.f, SY = 0.f;
#pragma unroll
        for (int dr = -2; dr <= 2; ++dr) {
            int r = pr + dr;
            if (r < 0 || r >= HH) continue;
#pragma unroll
            for (int dc = -2; dc <= 2; ++dc) {
                int cc = pc + dc;
                if (cc < 0 || cc >= WW) continue;
                float mv = map[r * WW + cc];
                S  += mv;
                SX += mv * (float)cc;
                SY += mv * (float)r;
            }
        }
        float x = (S == 0.f) ? (float)pc : (SX / S);
        float y = (S == 0.f) ? (float)pr : (SY / S);
        kx = x + 0.4395f;
        ky = y + 0.4395f;
        conf = 1.f;
    }
    out[t * 3 + 0] = kx;
    out[t * 3 + 1] = ky;
    out[t * 3 + 2] = conf;
}

extern "C" void kernel_launch(void* const* d_in, const int* in_sizes, int n_in,
                              void* d_out, int out_size, void* d_ws, size_t ws_size,
                              hipStream_t stream) {
    const float* in = (const float*)d_in[0];
    float* out = (float*)d_out;

    const int nstrips = NMAPS * NSTRIP;   // 4096
    float* sval = (float*)d_ws;
    int*   sidx = (int*)((char*)d_ws + (size_t)nstrips * 4);
    int*   scnt = (int*)((char*)d_ws + (size_t)nstrips * 8);

    blur_peak_strip<<<nstrips / 4, 256, 0, stream>>>(in, sval, sidx, scnt);
    finalize_kernel<<<(NMAPS + 255) / 256, 256, 0, stream>>>(in, sval, sidx, scnt, out);
}

// Round 14
// 81.912 us; speedup vs baseline: 1.2461x; 1.2461x over previous
//
#include <hip/hip_runtime.h>
#include <cmath>

#define HH 256
#define WW 256
#define RAD 12
#define KLEN 25
#define NMAPS 512
#define ESTRIP 32
#define NSTRIP (HH / ESTRIP)   // 8 strips per map
#define RING 29                // 24 carried + 5 fresh slots per macro-iter

typedef float v2f __attribute__((ext_vector_type(2)));

// ---------------------------------------------------------------------------
// Kernel A: 256-thread blocks = 4 INDEPENDENT strip-waves; 64 lanes x 4 cols.
// Software-pipelined row schedule (1-row skew, fully static) = R12 structure.
// R14: vertical conv accumulators split into even/odd tap chains (4 chains,
// ~13 deps each instead of 2 chains x 25) -> VC becomes issue-bound.
// Temporaries die before the LDS write; peak VGPR must stay <= 128
// (R13 lesson: crossing 128 drops residency 4->3 waves/SIMD, -28% perf).
// No min-waves launch-bounds arg (R9/R10: it caps VGPR and forces spill).
// ---------------------------------------------------------------------------
__global__ __launch_bounds__(256) void blur_peak_strip(
    const float* __restrict__ in,
    float* __restrict__ sval,
    int* __restrict__ sidx,
    int* __restrict__ scnt)
{
    __shared__ __align__(16) float vrow[4][2][WW + 2 * RAD];  // per-wave dbuf

    const int tid  = threadIdx.x;
    const int l    = tid & 63;           // lane, owns cols 4l..4l+3
    const int wv   = tid >> 6;
    const int sid  = blockIdx.x * 4 + wv;    // strip id 0..4095
    const int m     = sid >> 3;              // map
    const int strip = sid & 7;               // strip within map
    const float4* map4 = reinterpret_cast<const float4*>(in) + (size_t)m * (HH * WW / 4);

    const int e0 = strip * ESTRIP;
    const int o0 = e0 - 1;

    // Gaussian taps (identical float32 math to R2-R13; folds at compile time).
    float kf[KLEN];
    {
        float s = 0.f; float h[RAD + 1];
#pragma unroll
        for (int i = 0; i <= RAD; ++i) {
            float tt = (float)(i - RAD);
            h[i] = expf(-(tt * tt) / 18.0f);
            s += (i < RAD) ? 2.f * h[i] : h[i];
        }
#pragma unroll
        for (int i = 0; i <= RAD; ++i) h[i] /= s;
#pragma unroll
        for (int i = 0; i < KLEN; ++i) kf[i] = h[(i <= RAD) ? i : (2 * RAD - i)];
    }

    // Ring: slot i holds padded[oT + i], oT = o0 + 5*T; padded[q] = raw[mirr(q-12)]
    v2f rxy[RING], rzw[RING];
#pragma unroll
    for (int i = 0; i < RING; ++i) {
        int q = o0 + i - RAD;
        int r = (q < 0) ? (-q - 1) : q;    // top mirror only
        float4 t4 = map4[(size_t)r * (WW / 4) + l];
        rxy[i] = (v2f){t4.x, t4.y};
        rzw[i] = (v2f){t4.z, t4.w};
    }

    float4 g0v  = make_float4(0.f, 0.f, 0.f, 0.f);
    float4 gm1v = g0v, gm2v = g0v;
    float bval = -1.f;
    int   bidx = 0x7FFFFFFF;
    int   cnt  = 0;
    float4 pf0, pf1, pf2, pf3, pf4;

#define PREFETCH(TT)                                                          \
    {                                                                         \
        int rb = o0 + 5 * (TT) + 17;                                          \
        int r0 = rb, r1 = rb + 1, r2 = rb + 2, r3 = rb + 3, r4 = rb + 4;      \
        if (r0 > HH - 1) r0 = 2 * HH - 1 - r0;                                \
        if (r1 > HH - 1) r1 = 2 * HH - 1 - r1;                                \
        if (r2 > HH - 1) r2 = 2 * HH - 1 - r2;                                \
        if (r3 > HH - 1) r3 = 2 * HH - 1 - r3;                                \
        if (r4 > HH - 1) r4 = 2 * HH - 1 - r4;                                \
        pf0 = map4[(size_t)r0 * (WW / 4) + l];                                \
        pf1 = map4[(size_t)r1 * (WW / 4) + l];                                \
        pf2 = map4[(size_t)r2 * (WW / 4) + l];                                \
        pf3 = map4[(size_t)r3 * (WW / 4) + l];                                \
        pf4 = map4[(size_t)r4 * (WW / 4) + l];                                \
    }

#define ROTATE()                                                              \
    {                                                                         \
        _Pragma("unroll")                                                     \
        for (int i = 0; i < RING - 5; ++i) {                                  \
            rxy[i] = rxy[i + 5]; rzw[i] = rzw[i + 5];                         \
        }                                                                     \
        rxy[24] = (v2f){pf0.x, pf0.y}; rzw[24] = (v2f){pf0.z, pf0.w};         \
        rxy[25] = (v2f){pf1.x, pf1.y}; rzw[25] = (v2f){pf1.z, pf1.w};         \
        rxy[26] = (v2f){pf2.x, pf2.y}; rzw[26] = (v2f){pf2.z, pf2.w};         \
        rxy[27] = (v2f){pf3.x, pf3.y}; rzw[27] = (v2f){pf3.z, pf3.w};         \
        rxy[28] = (v2f){pf4.x, pf4.y}; rzw[28] = (v2f){pf4.z, pf4.w};         \
    }

// VC(t) from ring slots PP..PP+24 and write v(t) into buf[(TP)&1].
// R14: even/odd tap chain split — 4 short chains, combined once at the end.
#define VCW(PP, TP)                                                           \
    {                                                                         \
        v2f vxyA = (v2f){0.f, 0.f}, vxyB = (v2f){0.f, 0.f};                   \
        v2f vzwA = (v2f){0.f, 0.f}, vzwB = (v2f){0.f, 0.f};                   \
        _Pragma("unroll")                                                     \
        for (int d = 0; d < KLEN; d += 2) {                                   \
            vxyA += kf[d] * rxy[(PP) + d];                                    \
            vzwA += kf[d] * rzw[(PP) + d];                                    \
        }                                                                     \
        _Pragma("unroll")                                                     \
        for (int d = 1; d < KLEN; d += 2) {                                   \
            vxyB += kf[d] * rxy[(PP) + d];                                    \
            vzwB += kf[d] * rzw[(PP) + d];                                    \
        }                                                                     \
        v2f vxy = vxyA + vxyB;                                                \
        v2f vzw = vzwA + vzwB;                                                \
        float* wb = vrow[wv][(TP) & 1];                                       \
        reinterpret_cast<float4*>(wb + RAD)[l] =                              \
            make_float4(vxy.x, vxy.y, vzw.x, vzw.y);                          \
        if (l < 3)   reinterpret_cast<float4*>(wb)[2 - l]   =                 \
            make_float4(vzw.y, vzw.x, vxy.y, vxy.x);                          \
        if (l >= 61) reinterpret_cast<float4*>(wb)[130 - l] =                 \
            make_float4(vzw.y, vzw.x, vxy.y, vxy.x);                          \
    }

// HC of row held in rd0..rd6 -> shift g history (R12 scalar form: 4 chains)
#define HC()                                                                  \
    {                                                                         \
        float acc0 = 0.f, acc1 = 0.f, acc2 = 0.f, acc3 = 0.f;                 \
        const float4 rda[7] = {rd0, rd1, rd2, rd3, rd4, rd5, rd6};            \
        _Pragma("unroll")                                                     \
        for (int k = 0; k < 7; ++k) {                                         \
            _Pragma("unroll")                                                 \
            for (int e = 0; e < 4; ++e) {                                     \
                const int i = 4 * k + e;                                      \
                const float wval = (e == 0) ? rda[k].x : (e == 1) ? rda[k].y  \
                                 : (e == 2) ? rda[k].z : rda[k].w;            \
                if (i <= 24)           acc0 += kf[i]     * wval;              \
                if (i >= 1 && i <= 25) acc1 += kf[i - 1] * wval;              \
                if (i >= 2 && i <= 26) acc2 += kf[i - 2] * wval;              \
                if (i >= 3)            acc3 += kf[i - 3] * wval;              \
            }                                                                 \
        }                                                                     \
        gm2v = gm1v; gm1v = g0v;                                              \
        g0v = make_float4(acc0, acc1, acc2, acc3);                            \
    }

// eval row EROW (center gm1v), raw values from ring slot SLOT
#define EV(SLOT, EROW)                                                        \
    {                                                                         \
        const int erow = (EROW);                                              \
        float lf0 = __shfl_up(gm1v.w, 1);   if (l == 0)  lf0 = 0.f;           \
        float rt3 = __shfl_down(gm1v.x, 1); if (l == 63) rt3 = 0.f;           \
        const bool etop = (erow == 0), ebot = (erow == HH - 1);               \
        const float gm1a[4] = {gm1v.x, gm1v.y, gm1v.z, gm1v.w};               \
        const float gm2a[4] = {gm2v.x, gm2v.y, gm2v.z, gm2v.w};               \
        const float g0a[4]  = {g0v.x,  g0v.y,  g0v.z,  g0v.w};                \
        const float mva[4]  = {rxy[SLOT].x, rxy[SLOT].y,                      \
                               rzw[SLOT].x, rzw[SLOT].y};                     \
        _Pragma("unroll")                                                     \
        for (int q = 0; q < 4; ++q) {                                         \
            float gE = gm1a[q];                                               \
            float up = etop ? 0.f : gm2a[q];                                  \
            float dn = ebot ? 0.f : g0a[q];                                   \
            float lf = (q == 0) ? lf0 : gm1a[q - 1];                          \
            float rt = (q == 3) ? rt3 : gm1a[q + 1];                          \
            float mx = fmaxf(fmaxf(up, dn), fmaxf(lf, rt));                   \
            bool pk = (gE >= mx) && (gE > 0.01f);                             \
            cnt += pk ? 1 : 0;                                                \
            float mv = mva[q];                                                \
            int fi = erow * WW + 4 * l + q;                                   \
            bool upd = pk && (mv > bval);                                     \
            bval = upd ? mv : bval;                                           \
            bidx = upd ? fi : bidx;                                           \
        }                                                                     \
    }

// full pipelined row: t = 5*TB+PP. RD(t-1) -> VC(t)+write -> HC(t-1) -> EV(t-2)
#define ROW_FULL(TB, PP)                                                      \
    {                                                                         \
        const int tpar = ((TB) + (PP)) & 1;   /* parity of t since 5T+PP */   \
        const float4* rb4 =                                                   \
            reinterpret_cast<const float4*>(vrow[wv][tpar ^ 1]);              \
        float4 rd0 = rb4[l + 0], rd1 = rb4[l + 1], rd2 = rb4[l + 2],          \
               rd3 = rb4[l + 3], rd4 = rb4[l + 4], rd5 = rb4[l + 5],          \
               rd6 = rb4[l + 6];                                              \
        VCW(PP, tpar);                                                        \
        __builtin_amdgcn_wave_barrier();                                      \
        HC();                                                                 \
        EV((PP) + 10, o0 + 5 * (TB) + (PP) - 2);                              \
    }

// warmup row without eval (t = PP, TB=0)
#define ROW_NOEV(PP)                                                          \
    {                                                                         \
        const int tpar = (PP) & 1;                                            \
        const float4* rb4 =                                                   \
            reinterpret_cast<const float4*>(vrow[wv][tpar ^ 1]);              \
        float4 rd0 = rb4[l + 0], rd1 = rb4[l + 1], rd2 = rb4[l + 2],          \
               rd3 = rb4[l + 3], rd4 = rb4[l + 4], rd5 = rb4[l + 5],          \
               rd6 = rb4[l + 6];                                              \
        VCW(PP, PP);                                                          \
        __builtin_amdgcn_wave_barrier();                                      \
        HC();                                                                 \
    }

    // ---- T = 0: t=0 (VC only), t=1,2 (no eval), t=3,4 (full) ----
    PREFETCH(0);
    VCW(0, 0);
    __builtin_amdgcn_wave_barrier();
    ROW_NOEV(1);
    ROW_NOEV(2);
    ROW_FULL(0, 3);
    ROW_FULL(0, 4);
    ROTATE();

    // ---- main: T = 1..5, rows t = 5T..5T+4, all full ----
#pragma unroll 1
    for (int T = 1; T < 6; ++T) {
        PREFETCH(T);
        ROW_FULL(T, 0);
        ROW_FULL(T, 1);
        ROW_FULL(T, 2);
        ROW_FULL(T, 3);
        ROW_FULL(T, 4);
        ROTATE();
    }

    // ---- T = 6: t=30..33 full; t=34 tail (RD+HC+EV only) ----
    ROW_FULL(6, 0);
    ROW_FULL(6, 1);
    ROW_FULL(6, 2);
    ROW_FULL(6, 3);
    {
        // t = 34: read v(33) from buf[33&1]=buf[1], HC(33), EV(32)
        const float4* rb4 = reinterpret_cast<const float4*>(vrow[wv][1]);
        float4 rd0 = rb4[l + 0], rd1 = rb4[l + 1], rd2 = rb4[l + 2],
               rd3 = rb4[l + 3], rd4 = rb4[l + 4], rd5 = rb4[l + 5],
               rd6 = rb4[l + 6];
        HC();
        EV(14, o0 + 32);
    }

#undef ROW_NOEV
#undef ROW_FULL
#undef EV
#undef HC
#undef VCW
#undef ROTATE
#undef PREFETCH

    // ---- 64-lane butterfly: (max val, min idx on tie), sum count ----
#pragma unroll
    for (int off = 32; off > 0; off >>= 1) {
        float v2 = __shfl_xor(bval, off);
        int   i2 = __shfl_xor(bidx, off);
        int   c2 = __shfl_xor(cnt,  off);
        if (v2 > bval || (v2 == bval && i2 < bidx)) { bval = v2; bidx = i2; }
        cnt += c2;
    }
    if (l == 0) { sval[sid] = bval; sidx[sid] = bidx; scnt[sid] = cnt; }
}

// ---------------------------------------------------------------------------
// Kernel B: per-map combine strips + 5x5 window sums at winner + output logic
// ---------------------------------------------------------------------------
__global__ __launch_bounds__(256) void finalize_kernel(
    const float* __restrict__ in,
    const float* __restrict__ sval,
    const int* __restrict__ sidx,
    const int* __restrict__ scnt,
    float* __restrict__ out)
{
    int t = blockIdx.x * blockDim.x + threadIdx.x;
    if (t >= NMAPS) return;

    float BV = -1.f; int BI = 0x7FFFFFFF; int C = 0;
#pragma unroll
    for (int s2 = 0; s2 < NSTRIP; ++s2) {
        int k = t * NSTRIP + s2;
        float v = sval[k]; int i = sidx[k];
        if (v > BV || (v == BV && i < BI)) { BV = v; BI = i; }
        C += scnt[k];
    }

    bool valid = (C == 1) || ((C > 1) && (BV >= 0.8f));

    float kx = -999.999f, ky = -999.999f, conf = 0.f;
    if (valid) {
        int pr = BI / WW, pc = BI % WW;
        const float* map = in + (size_t)t * HH * WW;
        float S = 0.f, SX = 0.f, SY = 0.f;
#pragma unroll
        for (int dr = -2; dr <= 2; ++dr) {
            int r = pr + dr;
            if (r < 0 || r >= HH) continue;
#pragma unroll
            for (int dc = -2; dc <= 2; ++dc) {
                int cc = pc + dc;
                if (cc < 0 || cc >= WW) continue;
                float mv = map[r * WW + cc];
                S  += mv;
                SX += mv * (float)cc;
                SY += mv * (float)r;
            }
        }
        float x = (S == 0.f) ? (float)pc : (SX / S);
        float y = (S == 0.f) ? (float)pr : (SY / S);
        kx = x + 0.4395f;
        ky = y + 0.4395f;
        conf = 1.f;
    }
    out[t * 3 + 0] = kx;
    out[t * 3 + 1] = ky;
    out[t * 3 + 2] = conf;
}

extern "C" void kernel_launch(void* const* d_in, const int* in_sizes, int n_in,
                              void* d_out, int out_size, void* d_ws, size_t ws_size,
                              hipStream_t stream) {
    const float* in = (const float*)d_in[0];
    float* out = (float*)d_out;

    const int nstrips = NMAPS * NSTRIP;   // 4096
    float* sval = (float*)d_ws;
    int*   sidx = (int*)((char*)d_ws + (size_t)nstrips * 4);
    int*   scnt = (int*)((char*)d_ws + (size_t)nstrips * 8);

    blur_peak_strip<<<nstrips / 4, 256, 0, stream>>>(in, sval, sidx, scnt);
    finalize_kernel<<<(NMAPS + 255) / 256, 256, 0, stream>>>(in, sval, sidx, scnt, out);
}